// Round 19
// baseline (466.675 us; speedup 1.0000x reference)
//
#include <hip/hip_runtime.h>
#include <stdint.h>

#define M_DIM 8192
#define K_DIM 4096
#define N_DIM 4096
#define KTILES (K_DIM / 64)

typedef __attribute__((ext_vector_type(4))) int i32x4;

// ---------------------------------------------------------------------------
// Pack int32-stored int8 weights [N,K] -> fragment-major int8:
//   addr = ((n>>6)*64 + kt)*4096 + (n&3)*1024 + (g*16 + ((n&63)>>2))*16 + byte
// (n = b + 4r + j permutation baked in, R18-verified mapping; j-frags
//  adjacent so GEMM needs ONE B base pointer, j*1024 fits imm13.)
// Also corr[n] = (128 - zp) * rowsum[n].
// ---------------------------------------------------------------------------
__global__ void pack_w_kernel(const int* __restrict__ w, char* __restrict__ wp,
                              int* __restrict__ corr, const int* __restrict__ zpp) {
  __shared__ int red[256];
  const int n = blockIdx.x;
  const int t = threadIdx.x;  // kt = t>>2, g = t&3
  const int kt = t >> 2;
  const int g = t & 3;
  const int* row = w + (size_t)n * K_DIM + kt * 64 + g * 16;
  int s = 0;
  int words[4];
#pragma unroll
  for (int u = 0; u < 4; ++u) {
    int4 v = *(const int4*)(row + u * 4);
    s += v.x + v.y + v.z + v.w;
    words[u] = (v.x & 255) | ((v.y & 255) << 8) | ((v.z & 255) << 16) | (v.w << 24);
  }
  const int j = n & 3;
  const int r = (n & 63) >> 2;
  char* dst = wp + ((size_t)(n >> 6) * 64 + kt) * 4096 + j * 1024 + (g * 16 + r) * 16;
  *(int4*)dst = make_int4(words[0], words[1], words[2], words[3]);
  red[t] = s;
  __syncthreads();
  for (int off = 128; off > 0; off >>= 1) {
    if (t < off) red[t] += red[t + off];
    __syncthreads();
  }
  if (t == 0) corr[n] = (128 - zpp[0]) * red[0];
}

// ---------------------------------------------------------------------------
// Quantize fp32 input -> int8 (q-128) in fragment-major A layout:
//   addr = ((m>>7)*64 + kt)*8192 + ((m>>4)&7)*1024 + (g4*16 + (m&15))*16 + byte
// Block b handles rows 16b..16b+15; thread (t,iter u): kt = u*4 + (t>>6),
// slot = t&63 (g4 = slot>>4, r = slot&15). Writes perfectly coalesced
// (64 lanes -> 1KB contiguous); reads are full 64B lines per thread.
// ---------------------------------------------------------------------------
__global__ void quant_in_kernel(const float* __restrict__ x, char* __restrict__ q,
                                const float* __restrict__ sp, const int* __restrict__ zpp) {
  const int b = blockIdx.x;   // 16-row group, 0..511
  const int t = threadIdx.x;  // 0..255
  const float s = sp[0];
  const float zp = (float)zpp[0];
  const int slot = t & 63;
  const int g4 = slot >> 4;
  const int r = slot & 15;
  const float* src0 = x + (size_t)(16 * b + r) * K_DIM + g4 * 16;
  char* dst0 = q + (size_t)(b >> 3) * 524288 + (b & 7) * 1024 + slot * 16;
#pragma unroll 4
  for (int u = 0; u < 16; ++u) {
    const int kt = u * 4 + (t >> 6);
    const float4* src = (const float4*)(src0 + kt * 64);
    int words[4];
#pragma unroll
    for (int v4 = 0; v4 < 4; ++v4) {
      float4 v = src[v4];
      int b0 = (int)fminf(fmaxf(rintf(v.x / s) + zp, 0.f), 255.f) - 128;
      int b1 = (int)fminf(fmaxf(rintf(v.y / s) + zp, 0.f), 255.f) - 128;
      int b2 = (int)fminf(fmaxf(rintf(v.z / s) + zp, 0.f), 255.f) - 128;
      int b3 = (int)fminf(fmaxf(rintf(v.w / s) + zp, 0.f), 255.f) - 128;
      words[v4] = (b0 & 255) | ((b1 & 255) << 8) | ((b2 & 255) << 16) | (b3 << 24);
    }
    *(int4*)(dst0 + (size_t)kt * 8192) = make_int4(words[0], words[1], words[2], words[3]);
  }
}

// ---------------------------------------------------------------------------
// 256x256 i8 GEMM with ZERO LDS: both operands fragment-packed in global.
// Every frag load = ONE coalesced 1KB global_load_dwordx4 (lane i -> +i*16).
// Rationale: R3-R18 floor = LDS term (~1200-1500 cyc/tile) serialized against
// MFMA (1306) under barrier lockstep. No LDS -> no staging, no syncthreads;
// per tile/wave: 12 loads (prefetch dist 1, ping-pong regs) + 32 MFMA +
// counted vmcnt(12) + RAW s_barrier (no drain; keeps 8 waves aligned so the
// 32KB/tile unique set stays L1/L2-hot; A-frags shared x4 waves, B x2).
// Geometry: 512 thr = 8 waves (2M x 4N), 128x64 out/wave, BK=64,
// mfma_i32_16x16x64_i8. Regs: acc 128 + frags 96 + ptrs ~8 = ~235 < 256.
// Ledger: BODY(T) issues T+1's 12 loads then vmcnt(12) -> T's 12 retired
// before MFMA; tail BODY skips issue and uses vmcnt(0).
// Epilogue (int8 layers) writes fragment-packed A for the NEXT layer;
// layer 3 writes plain fp32 [M,N] (R9-validated packed full-line stores).
// ---------------------------------------------------------------------------
#define RD(p) (*(const i32x4*)(p))

#define BODY(TNEXT, CA, CB, NA, NB, DO_NEXT)                                  \
  {                                                                           \
    if (DO_NEXT) {                                                            \
      const char* aT_ = abase + (size_t)(TNEXT) * 8192;                       \
      const char* bT_ = bbase + (size_t)(TNEXT) * 4096;                       \
      _Pragma("unroll") for (int i_ = 0; i_ < 8; ++i_)                        \
          NA[i_] = RD(aT_ + i_ * 1024);                                       \
      _Pragma("unroll") for (int j_ = 0; j_ < 4; ++j_)                        \
          NB[j_] = RD(bT_ + j_ * 1024);                                       \
      asm volatile("s_waitcnt vmcnt(12)" ::: "memory");                       \
    } else {                                                                  \
      asm volatile("s_waitcnt vmcnt(0)" ::: "memory");                        \
    }                                                                         \
    __builtin_amdgcn_s_barrier();                                             \
    __builtin_amdgcn_s_setprio(1);                                            \
    _Pragma("unroll") for (int i_ = 0; i_ < 8; ++i_)                          \
        _Pragma("unroll") for (int j_ = 0; j_ < 4; ++j_)                      \
            acc[i_][j_] = __builtin_amdgcn_mfma_i32_16x16x64_i8(              \
                CA[i_], CB[j_], acc[i_][j_], 0, 0, 0);                        \
    __builtin_amdgcn_s_setprio(0);                                            \
  }

template <int WRITE_Q>
__global__ __launch_bounds__(512, 2) void gemm_kernel(
    const char* __restrict__ qa, const char* __restrict__ wbp,
    const int* __restrict__ corr, const float* __restrict__ swp,
    const float* __restrict__ bias, const float* __restrict__ sp,
    const int* __restrict__ zpp, char* __restrict__ outq, float* __restrict__ outf) {
  const int tid = threadIdx.x;
  const int lane = tid & 63;
  const int w = tid >> 6;
  const int wr = w >> 2;   // 0..1 (M)
  const int wc = w & 3;    // 0..3 (N)
  const int bid = blockIdx.x;
  const int bm = bid & 31;  // M/256 = 32, fastest: neighbors share B panel
  const int bn = bid >> 5;  // N/256 = 16

  // --- single base pointers into fragment-packed A and B ---
  const char* abase = qa + (size_t)(bm * 2 + wr) * 524288 + lane * 16;
  const char* bbase = wbp + (size_t)(bn * 4 + wc) * 262144 + lane * 16;

  i32x4 acc[8][4] = {};
  i32x4 ca[8], cb[4], na[8], nb[4];

  // --- prologue: load tile 0 ---
#pragma unroll
  for (int i = 0; i < 8; ++i) ca[i] = RD(abase + i * 1024);
#pragma unroll
  for (int j = 0; j < 4; ++j) cb[j] = RD(bbase + j * 1024);

  // --- main loop: ping-pong bodies; BODY(T+1,...) = loads for next tile ---
  for (int t = 0; t < KTILES - 2; t += 2) {
    BODY(t + 1, ca, cb, na, nb, 1)
    BODY(t + 2, na, nb, ca, cb, 1)
  }
  BODY(KTILES - 1, ca, cb, na, nb, 1)  // t = 62, loads tile 63
  BODY(0, na, nb, ca, cb, 0)           // t = 63, no loads, vmcnt(0)

  // --- epilogue: frag j, lane c -> n = nb4 + j (consecutive) ---
  const float s = sp[0];
  const float zpf = (float)zpp[0];
  const int c = lane & 15;
  const int qg = lane >> 4;
  const int m0 = bm * 256 + wr * 128 + qg * 4;
  const int nb4 = bn * 256 + wc * 64 + (c << 2);
  const int4 cr4 = *(const int4*)(corr + nb4);
  const float4 sw4 = *(const float4*)(swp + nb4);
  const float4 bb4 = *(const float4*)(bias + nb4);
  const float fs0 = s * sw4.x, fs1 = s * sw4.y, fs2 = s * sw4.z, fs3 = s * sw4.w;
  // packed-A dest base for int8 layers (next layer's fragment layout):
  char* qdst = outq
                   ? outq + ((size_t)(bm * 2 + wr) * 64 + bn * 4 + wc) * 8192 +
                         ((c >> 2) * 16) * 16 + 4 * (c & 3)
                   : nullptr;
#pragma unroll
  for (int i = 0; i < 8; ++i) {
#pragma unroll
    for (int q = 0; q < 4; ++q) {
      const int m = m0 + i * 16 + q;
      const float v0 = fs0 * (float)(acc[i][0][q] + cr4.x) + bb4.x;
      const float v1 = fs1 * (float)(acc[i][1][q] + cr4.y) + bb4.y;
      const float v2 = fs2 * (float)(acc[i][2][q] + cr4.z) + bb4.z;
      const float v3 = fs3 * (float)(acc[i][3][q] + cr4.w) + bb4.w;
      if (WRITE_Q) {
        const int b0i = (int)fminf(fmaxf(rintf(v0 / s) + zpf, 0.f), 255.f) - 128;
        const int b1i = (int)fminf(fmaxf(rintf(v1 / s) + zpf, 0.f), 255.f) - 128;
        const int b2i = (int)fminf(fmaxf(rintf(v2 / s) + zpf, 0.f), 255.f) - 128;
        const int b3i = (int)fminf(fmaxf(rintf(v3 / s) + zpf, 0.f), 255.f) - 128;
        const uint32_t pk = (uint32_t)(b0i & 255) | ((uint32_t)(b1i & 255) << 8) |
                            ((uint32_t)(b2i & 255) << 16) | ((uint32_t)b3i << 24);
        // addr: + i*1024 + r*16 where r = qg*4 + q (m & 15)
        *(uint32_t*)(qdst + i * 1024 + (qg * 4 + q) * 16) = pk;
      } else {
        float4 o4;
        o4.x = v0; o4.y = v1; o4.z = v2; o4.w = v3;
        *(float4*)(outf + (size_t)m * N_DIM + nb4) = o4;
      }
    }
  }
}

// ---------------------------------------------------------------------------
extern "C" void kernel_launch(void* const* d_in, const int* in_sizes, int n_in,
                              void* d_out, int out_size, void* d_ws, size_t ws_size,
                              hipStream_t stream) {
  const float* x = (const float*)d_in[0];
  const int* wq = (const int*)d_in[1];
  const float* bias = (const float*)d_in[2];
  const float* s_in = (const float*)d_in[3];
  const int* zp_in = (const int*)d_in[4];
  const float* s_w = (const float*)d_in[5];
  float* out = (float*)d_out;

  const size_t WP_BYTES = (size_t)N_DIM * K_DIM;  // 16 MB packed int8 W
  const size_t Q_BYTES = (size_t)M_DIM * K_DIM;   // 32 MB packed int8 act
  char* ws = (char*)d_ws;
  char* wp = ws;
  char* q1 = ws + WP_BYTES;
  char* q2 = q1 + Q_BYTES;
  int* corr = (int*)(q2 + Q_BYTES);
  const size_t NEEDED = WP_BYTES + 2 * Q_BYTES + (size_t)N_DIM * sizeof(int);
  if (ws_size < NEEDED) return;

  pack_w_kernel<<<N_DIM, 256, 0, stream>>>(wq, wp, corr, zp_in);
  quant_in_kernel<<<M_DIM / 16, 256, 0, stream>>>(x, q1, s_in, zp_in);

  dim3 grid((M_DIM / 256) * (N_DIM / 256));  // 512 blocks
  dim3 blk(512);
  gemm_kernel<1><<<grid, blk, 0, stream>>>(q1, wp, corr, s_w, bias, s_in, zp_in, q2, nullptr);
  gemm_kernel<1><<<grid, blk, 0, stream>>>(q2, wp, corr, s_w, bias, s_in, zp_in, q1, nullptr);
  gemm_kernel<0><<<grid, blk, 0, stream>>>(q1, wp, corr, s_w, bias, s_in, zp_in, nullptr, out);
}

// Round 20
// 449.305 us; speedup vs baseline: 1.0387x; 1.0387x over previous
//
#include <hip/hip_runtime.h>
#include <stdint.h>

#define M_DIM 8192
#define K_DIM 4096
#define N_DIM 4096
#define KTILES (K_DIM / 64)

typedef __attribute__((ext_vector_type(4))) int i32x4;

// ---------------------------------------------------------------------------
// Pack int32-stored int8 weights [N,K] -> fragment-major int8 (R18/R19-
// verified): addr = ((n>>6)*64 + kt)*4096 + (n&3)*1024
//                   + (g*16 + ((n&63)>>2))*16 + byte
// (baked-in n = b+4r+j permutation -> epilogue n = base+4c+j consecutive;
//  a wave's B-fragment = ONE coalesced 1KB region.)
// Also corr[n] = (128 - zp) * rowsum[n].
// ---------------------------------------------------------------------------
__global__ void pack_w_kernel(const int* __restrict__ w, char* __restrict__ wp,
                              int* __restrict__ corr, const int* __restrict__ zpp) {
  __shared__ int red[256];
  const int n = blockIdx.x;
  const int t = threadIdx.x;  // kt = t>>2, g = t&3
  const int kt = t >> 2;
  const int g = t & 3;
  const int* row = w + (size_t)n * K_DIM + kt * 64 + g * 16;
  int s = 0;
  int words[4];
#pragma unroll
  for (int u = 0; u < 4; ++u) {
    int4 v = *(const int4*)(row + u * 4);
    s += v.x + v.y + v.z + v.w;
    words[u] = (v.x & 255) | ((v.y & 255) << 8) | ((v.z & 255) << 16) | (v.w << 24);
  }
  const int j = n & 3;
  const int r = (n & 63) >> 2;
  char* dst = wp + ((size_t)(n >> 6) * 64 + kt) * 4096 + j * 1024 + (g * 16 + r) * 16;
  *(int4*)dst = make_int4(words[0], words[1], words[2], words[3]);
  red[t] = s;
  __syncthreads();
  for (int off = 128; off > 0; off >>= 1) {
    if (t < off) red[t] += red[t + off];
    __syncthreads();
  }
  if (t == 0) corr[n] = (128 - zpp[0]) * red[0];
}

// ---------------------------------------------------------------------------
// Quantize fp32 input -> int8 (q - 128), 4 elements/thread (row-major).
// ---------------------------------------------------------------------------
__global__ void quant_in_kernel(const float* __restrict__ x, char* __restrict__ q,
                                const float* __restrict__ sp, const int* __restrict__ zpp) {
  const int i = blockIdx.x * blockDim.x + threadIdx.x;
  const float s = sp[0];
  const float zp = (float)zpp[0];
  float4 v = ((const float4*)x)[i];
  float t0 = fminf(fmaxf(rintf(v.x / s) + zp, 0.f), 255.f);
  float t1 = fminf(fmaxf(rintf(v.y / s) + zp, 0.f), 255.f);
  float t2 = fminf(fmaxf(rintf(v.z / s) + zp, 0.f), 255.f);
  float t3 = fminf(fmaxf(rintf(v.w / s) + zp, 0.f), 255.f);
  int b0 = (int)t0 - 128, b1 = (int)t1 - 128, b2 = (int)t2 - 128, b3 = (int)t3 - 128;
  ((int*)q)[i] = (b0 & 255) | ((b1 & 255) << 8) | ((b2 & 255) << 16) | (b3 << 24);
}

// ---------------------------------------------------------------------------
// 256x256 i8 GEMM: R15's thin-wave TLP (16 waves, 4/SIMD, 64x64 out/wave)
// x B-DIRECT from fragment-packed global (4 coalesced 1KB loads/wave/tile,
// prefetched 1 full tile ahead, ping-pong regs). A stays in LDS (ring-4 x
// 16KB = 64KB, swizzled): LDS traffic drops 160->80 KB/tile (~960 cyc <
// MFMA 1306) -- the R15 limiter. R18 proved the pack correct; R15 proved
// 4 waves/SIMD hides load latency; this combines them.
// Regs/wave: acc 4x4 = 64 AGPR + ~60 VGPR (a_ 16 transient, B ping-pong 32,
// addr) -- inside the (1024,4) 128-unified cap R15 validated.
// Ledger (5 vmem ops/tile: 4 B(t+1) + 1 Astage(t+3)): end-of-t vmcnt(5)
// retires t-1's ops -> B(t) before MFMA(t) [vmcnt precedes MFMA in body],
// stage(t+2) before its t+2 read. Stage(t) targets slot (t+3)&3 = (t-1)&3,
// read-complete before t-1's end barrier. Prologue [stage0, B0 x4, stage1,
// stage2] + vmcnt(2) confirms slot0 + B0. Tail: clamped dead stages;
// last tile vmcnt(0).
// Swizzle (0-conflict R1-R19): phys 16B slot = g ^ ((row>>1)&3) on staging
// source and ds_read addr. Epilogue: R9/R15-validated packed full-line
// stores (n = base + 4c + j consecutive via the baked B permutation).
// ---------------------------------------------------------------------------
#define STAGE16(SRC, DST)                                                     \
  __builtin_amdgcn_global_load_lds(                                           \
      (const __attribute__((address_space(1))) void*)(SRC),                   \
      (__attribute__((address_space(3))) void*)(DST), 16, 0, 0)

#define RD(p) (*(const i32x4*)(p))

#define TILEB(SLOT, KSTG, TBN, BC, BN_, DO_NEXT)                              \
  {                                                                           \
    const char* cA_ = &lds[SLOT][0];                                          \
    char* nA_ = &lds[((SLOT) + 3) & 3][0];                                    \
    i32x4 a_[4];                                                              \
    _Pragma("unroll") for (int i_ = 0; i_ < 4; ++i_)                          \
        a_[i_] = RD(cA_ + aoff[i_]);                                          \
    if (DO_NEXT) {                                                            \
      _Pragma("unroll") for (int j_ = 0; j_ < 4; ++j_)                        \
          BN_[j_] = RD(bbase + (size_t)(TBN) * 4096 + j_ * 1024);             \
      STAGE16(asrc0 + (size_t)(KSTG) * 64, nA_ + o0_);                        \
      asm volatile("s_waitcnt vmcnt(5)" ::: "memory");                        \
    } else {                                                                  \
      asm volatile("s_waitcnt vmcnt(0)" ::: "memory");                        \
    }                                                                         \
    __builtin_amdgcn_s_barrier();                                             \
    __builtin_amdgcn_s_setprio(1);                                            \
    _Pragma("unroll") for (int i_ = 0; i_ < 4; ++i_)                          \
        _Pragma("unroll") for (int j_ = 0; j_ < 4; ++j_)                      \
            acc[i_][j_] = __builtin_amdgcn_mfma_i32_16x16x64_i8(              \
                a_[i_], BC[j_], acc[i_][j_], 0, 0, 0);                        \
    __builtin_amdgcn_s_setprio(0);                                            \
  }

template <int WRITE_Q>
__global__ __launch_bounds__(1024, 4) void gemm_kernel(
    const char* __restrict__ qa, const char* __restrict__ wbp,
    const int* __restrict__ corr, const float* __restrict__ swp,
    const float* __restrict__ bias, const float* __restrict__ sp,
    const int* __restrict__ zpp, char* __restrict__ outq, float* __restrict__ outf) {
  __shared__ __align__(16) char lds[4][16384];  // 64 KB: A-only 4-slot ring
  const int tid = threadIdx.x;
  const int lane = tid & 63;
  const int w = tid >> 6;   // 16 waves
  const int wr = w >> 2;    // 0..3 (M, 64 each)
  const int wc = w & 3;     // 0..3 (N, 64 each)
  const int bid = blockIdx.x;
  const int bm = bid & 31;  // M/256 = 32, fastest: neighbors share B panel
  const int bn = bid >> 5;  // N/256 = 16
  const char* abase = qa + (size_t)bm * 256 * K_DIM;

  // --- A staging: 1024 thr x 16B = whole 16KB tile in ONE gload_lds ---
  const int o0_ = tid * 16;
  const int r0_ = tid >> 2;            // tile row 0..255
  const int sl_ = tid & 3;
  const int g0_ = sl_ ^ ((r0_ >> 1) & 3);
  const char* asrc0 = abase + (size_t)r0_ * K_DIM + g0_ * 16;

  // --- B direct: single base into fragment-packed panel ---
  const char* bbase = wbp + (size_t)(bn * 4 + wc) * 262144 + lane * 16;

  // --- per-lane A ds_read byte offsets (swizzled) ---
  const int rr = lane & 15;
  const int g = lane >> 4;
  int aoff[4];
#pragma unroll
  for (int i = 0; i < 4; ++i) {
    const int rowA = wr * 64 + i * 16 + rr;
    aoff[i] = (rowA << 6) + ((g ^ ((rowA >> 1) & 3)) << 4);
  }

  i32x4 acc[4][4] = {};
  i32x4 bA[4], bB[4];

  // --- prologue: [stage0][B0 x4][stage1][stage2]; vmcnt(2) -> slot0+B0 ---
  STAGE16(asrc0, &lds[0][o0_]);
#pragma unroll
  for (int j = 0; j < 4; ++j) bA[j] = RD(bbase + j * 1024);
  STAGE16(asrc0 + 64, &lds[1][o0_]);
  STAGE16(asrc0 + 128, &lds[2][o0_]);
  asm volatile("s_waitcnt vmcnt(2)" ::: "memory");
  __builtin_amdgcn_s_barrier();

  // --- main loop: 60 tiles in 15 x 4; B ping-pong parity even=bA odd=bB ---
  for (int tb = 0; tb < 15; ++tb) {
    const int t0 = tb * 4;
    TILEB(0, t0 + 3, t0 + 1, bA, bB, 1)
    TILEB(1, t0 + 4, t0 + 2, bB, bA, 1)
    TILEB(2, t0 + 5, t0 + 3, bA, bB, 1)
    TILEB(3, t0 + 6, t0 + 4, bB, bA, 1)
  }
  // --- tail t = 60..63: stage clamps to 63 (dead re-stages) ---
  TILEB(0, KTILES - 1, 61, bA, bB, 1)
  TILEB(1, KTILES - 1, 62, bB, bA, 1)
  TILEB(2, KTILES - 1, 63, bA, bB, 1)
  TILEB(3, 0, 0, bB, bA, 0)

  // --- epilogue (R9/R15-validated): frag j, lane c -> n = nb4 + j ---
  const float s = sp[0];
  const float zpf = (float)zpp[0];
  const int m0 = bm * 256 + wr * 64 + (lane >> 4) * 4;
  const int nb4 = bn * 256 + wc * 64 + ((lane & 15) << 2);
  const int4 cr4 = *(const int4*)(corr + nb4);
  const float4 sw4 = *(const float4*)(swp + nb4);
  const float4 bb4 = *(const float4*)(bias + nb4);
  const float fs0 = s * sw4.x, fs1 = s * sw4.y, fs2 = s * sw4.z, fs3 = s * sw4.w;
#pragma unroll
  for (int i = 0; i < 4; ++i) {
#pragma unroll
    for (int q = 0; q < 4; ++q) {
      const int m = m0 + i * 16 + q;
      const float v0 = fs0 * (float)(acc[i][0][q] + cr4.x) + bb4.x;
      const float v1 = fs1 * (float)(acc[i][1][q] + cr4.y) + bb4.y;
      const float v2 = fs2 * (float)(acc[i][2][q] + cr4.z) + bb4.z;
      const float v3 = fs3 * (float)(acc[i][3][q] + cr4.w) + bb4.w;
      if (WRITE_Q) {
        const int b0i = (int)fminf(fmaxf(rintf(v0 / s) + zpf, 0.f), 255.f) - 128;
        const int b1i = (int)fminf(fmaxf(rintf(v1 / s) + zpf, 0.f), 255.f) - 128;
        const int b2i = (int)fminf(fmaxf(rintf(v2 / s) + zpf, 0.f), 255.f) - 128;
        const int b3i = (int)fminf(fmaxf(rintf(v3 / s) + zpf, 0.f), 255.f) - 128;
        const uint32_t pk = (uint32_t)(b0i & 255) | ((uint32_t)(b1i & 255) << 8) |
                            ((uint32_t)(b2i & 255) << 16) | ((uint32_t)b3i << 24);
        *(uint32_t*)(outq + (size_t)m * N_DIM + nb4) = pk;
      } else {
        float4 o4;
        o4.x = v0; o4.y = v1; o4.z = v2; o4.w = v3;
        *(float4*)(outf + (size_t)m * N_DIM + nb4) = o4;
      }
    }
  }
}

// ---------------------------------------------------------------------------
extern "C" void kernel_launch(void* const* d_in, const int* in_sizes, int n_in,
                              void* d_out, int out_size, void* d_ws, size_t ws_size,
                              hipStream_t stream) {
  const float* x = (const float*)d_in[0];
  const int* wq = (const int*)d_in[1];
  const float* bias = (const float*)d_in[2];
  const float* s_in = (const float*)d_in[3];
  const int* zp_in = (const int*)d_in[4];
  const float* s_w = (const float*)d_in[5];
  float* out = (float*)d_out;

  const size_t WP_BYTES = (size_t)N_DIM * K_DIM;  // 16 MB packed int8 W
  const size_t Q_BYTES = (size_t)M_DIM * K_DIM;   // 32 MB int8 activations
  char* ws = (char*)d_ws;
  char* wp = ws;
  char* q1 = ws + WP_BYTES;
  char* q2 = q1 + Q_BYTES;
  int* corr = (int*)(q2 + Q_BYTES);
  const size_t NEEDED = WP_BYTES + 2 * Q_BYTES + (size_t)N_DIM * sizeof(int);
  if (ws_size < NEEDED) return;

  pack_w_kernel<<<N_DIM, 256, 0, stream>>>(wq, wp, corr, zp_in);
  quant_in_kernel<<<(M_DIM * K_DIM / 4) / 256, 256, 0, stream>>>(x, q1, s_in, zp_in);

  dim3 grid((M_DIM / 256) * (N_DIM / 256));  // 512 blocks
  dim3 blk(1024);
  gemm_kernel<1><<<grid, blk, 0, stream>>>(q1, wp, corr, s_w, bias, s_in, zp_in, q2, nullptr);
  gemm_kernel<1><<<grid, blk, 0, stream>>>(q2, wp, corr, s_w, bias, s_in, zp_in, q1, nullptr);
  gemm_kernel<0><<<grid, blk, 0, stream>>>(q1, wp, corr, s_w, bias, s_in, zp_in, nullptr, out);
}

// Round 21
// 437.121 us; speedup vs baseline: 1.0676x; 1.0279x over previous
//
#include <hip/hip_runtime.h>
#include <stdint.h>

#define M_DIM 8192
#define K_DIM 4096
#define N_DIM 4096
#define KTILES (K_DIM / 64)

typedef __attribute__((ext_vector_type(4))) int i32x4;

// ---------------------------------------------------------------------------
// FINAL (R21 = R15 restore, measured optimum: 438.8us total, 131.3us/GEMM,
// MfmaUtil 49, occupancy 39.5%, 0 bank conflicts, WRITE_SIZE exactly 32MB).
// Design summary after 20 rounds of structural exploration:
//  - uint8/int8 integer GEMM via mfma_i32_16x16x64_i8 (exact i32 dot),
//    activation shift q-128 folded into per-channel corr[n].
//  - 3 chained layers; intermediate activations stay int8 (re-quantized in
//    the GEMM epilogue) -> whole working set ~80MB, L2/L3-resident.
//  - 256x256 tile, 1024 thr = 16 THIN waves (4/SIMD, 64x64 out/wave, acc
//    4x4 frags = 64 AGPR, VGPR 64): max TLP under the 512-reg/SIMD wall.
//  - LDS 4-slot ring (A16K+B16K) = 128KB, whole-tile staging (1 gload_lds
//    per matrix per tile), counted vmcnt(2)/tile, one barrier/tile.
//  - 0-conflict XOR swizzle: phys 16B slot = g ^ ((row>>1)&3) applied to
//    the inverse-swizzled global source AND the ds_read addr.
//  - B content permutation (LDS row rho holds weight row
//    (rho&~63)+4*(rho&15)+((rho>>4)&3)) -> epilogue n = base+4c+j
//    consecutive -> packed full-line stores (u32 int8 / float4 fp32).
// Structural ceiling: register file forces >=4x LDS read amplification ->
// LDS term (~1100 cyc/tile) = MFMA term (1306); barrier-synced waves can't
// overlap them further at HIP source level (pins/stagger/cadence/blocks all
// tested, all <= this config).
// ---------------------------------------------------------------------------
__global__ void pack_w_kernel(const int* __restrict__ w, char* __restrict__ wp,
                              int* __restrict__ corr, const int* __restrict__ zpp) {
  __shared__ int red[256];
  const int n = blockIdx.x;
  const int t = threadIdx.x;
  const int4* row = (const int4*)(w + (size_t)n * K_DIM);
  int s = 0;
  int words[4];
#pragma unroll
  for (int u = 0; u < 4; ++u) {
    int4 v = row[t * 4 + u];
    s += v.x + v.y + v.z + v.w;
    words[u] = (v.x & 255) | ((v.y & 255) << 8) | ((v.z & 255) << 16) | (v.w << 24);
  }
  ((int4*)(wp + (size_t)n * K_DIM))[t] = make_int4(words[0], words[1], words[2], words[3]);
  red[t] = s;
  __syncthreads();
  for (int off = 128; off > 0; off >>= 1) {
    if (t < off) red[t] += red[t + off];
    __syncthreads();
  }
  if (t == 0) corr[n] = (128 - zpp[0]) * red[0];
}

__global__ void quant_in_kernel(const float* __restrict__ x, char* __restrict__ q,
                                const float* __restrict__ sp, const int* __restrict__ zpp) {
  const int i = blockIdx.x * blockDim.x + threadIdx.x;
  const float s = sp[0];
  const float zp = (float)zpp[0];
  float4 v = ((const float4*)x)[i];
  float t0 = fminf(fmaxf(rintf(v.x / s) + zp, 0.f), 255.f);
  float t1 = fminf(fmaxf(rintf(v.y / s) + zp, 0.f), 255.f);
  float t2 = fminf(fmaxf(rintf(v.z / s) + zp, 0.f), 255.f);
  float t3 = fminf(fmaxf(rintf(v.w / s) + zp, 0.f), 255.f);
  int b0 = (int)t0 - 128, b1 = (int)t1 - 128, b2 = (int)t2 - 128, b3 = (int)t3 - 128;
  ((int*)q)[i] = (b0 & 255) | ((b1 & 255) << 8) | ((b2 & 255) << 16) | (b3 << 24);
}

#define STAGE16(SRC, DST)                                                     \
  __builtin_amdgcn_global_load_lds(                                           \
      (const __attribute__((address_space(1))) void*)(SRC),                   \
      (__attribute__((address_space(3))) void*)(DST), 16, 0, 0)

#define RD(p) (*(const i32x4*)(p))

#define TILE4(SLOT, KS)                                                       \
  {                                                                           \
    const char* cA_ = &lds[SLOT][0][0];                                       \
    const char* cB_ = &lds[SLOT][1][0];                                       \
    char* nA_ = &lds[((SLOT) + 3) & 3][0][0];                                 \
    char* nB_ = &lds[((SLOT) + 3) & 3][1][0];                                 \
    i32x4 a_[4], b_[4];                                                       \
    _Pragma("unroll") for (int i_ = 0; i_ < 4; ++i_)                          \
        a_[i_] = RD(cA_ + aoff[i_]);                                          \
    _Pragma("unroll") for (int j_ = 0; j_ < 4; ++j_)                          \
        b_[j_] = RD(cB_ + boff[j_]);                                          \
    STAGE16(asrc0 + (size_t)(KS), nA_ + o0_);                                 \
    STAGE16(bsrc0 + (size_t)(KS), nB_ + o0_);                                 \
    __builtin_amdgcn_s_setprio(1);                                            \
    _Pragma("unroll") for (int i_ = 0; i_ < 4; ++i_)                          \
        _Pragma("unroll") for (int j_ = 0; j_ < 4; ++j_)                      \
            acc[i_][j_] = __builtin_amdgcn_mfma_i32_16x16x64_i8(              \
                a_[i_], b_[j_], acc[i_][j_], 0, 0, 0);                        \
    __builtin_amdgcn_s_setprio(0);                                            \
    asm volatile("s_waitcnt vmcnt(2)" ::: "memory");                          \
    __builtin_amdgcn_s_barrier();                                             \
  }

template <int WRITE_Q>
__global__ __launch_bounds__(1024, 4) void gemm_kernel(
    const char* __restrict__ qa, const char* __restrict__ wb,
    const int* __restrict__ corr, const float* __restrict__ swp,
    const float* __restrict__ bias, const float* __restrict__ sp,
    const int* __restrict__ zpp, char* __restrict__ outq, float* __restrict__ outf) {
  __shared__ __align__(16) char lds[4][2][16384];  // 128 KB: 4-slot ring
  const int tid = threadIdx.x;
  const int lane = tid & 63;
  const int w = tid >> 6;   // 16 waves
  const int wr = w >> 2;    // 0..3 (M, 64 each)
  const int wc = w & 3;     // 0..3 (N, 64 each)
  const int bid = blockIdx.x;
  const int bm = bid & 31;  // M/256 = 32, fastest: neighbors share B panel
  const int bn = bid >> 5;  // N/256 = 16
  const char* abase = qa + (size_t)bm * 256 * K_DIM;
  const char* bbase = wb + (size_t)bn * 256 * K_DIM;

  // --- staging constants: 1024 thr x 16B = 16 KB (whole matrix tile) ---
  const int o0_ = tid * 16;
  const int r0_ = tid >> 2;            // tile row 0..255
  const int sl_ = tid & 3;             // 16B slot within row
  const int g0_ = sl_ ^ ((r0_ >> 1) & 3);
  const char* asrc0 = abase + (size_t)r0_ * K_DIM + g0_ * 16;
  // B content permutation: LDS row rho holds weight row (rho&~63)+4*(rho&15)+((rho>>4)&3)
  const int p0_ = (r0_ & ~63) + 4 * (r0_ & 15) + ((r0_ >> 4) & 3);
  const char* bsrc0 = bbase + (size_t)p0_ * K_DIM + g0_ * 16;

  // --- per-lane ds_read byte offsets (swizzled) ---
  const int rr = lane & 15;
  const int g = lane >> 4;
  int aoff[4], boff[4];
#pragma unroll
  for (int i = 0; i < 4; ++i) {
    const int rowA = wr * 64 + i * 16 + rr;
    aoff[i] = (rowA << 6) + ((g ^ ((rowA >> 1) & 3)) << 4);
    const int rowB = wc * 64 + i * 16 + rr;
    boff[i] = (rowB << 6) + ((g ^ ((rowB >> 1) & 3)) << 4);
  }

  i32x4 acc[4][4] = {};

  // --- prologue: stage slots 0,1,2 (6 ops); vmcnt(2) confirms slots 0,1 ---
  STAGE16(asrc0, &lds[0][0][o0_]);       STAGE16(bsrc0, &lds[0][1][o0_]);
  STAGE16(asrc0 + 64, &lds[1][0][o0_]);  STAGE16(bsrc0 + 64, &lds[1][1][o0_]);
  STAGE16(asrc0 + 128, &lds[2][0][o0_]); STAGE16(bsrc0 + 128, &lds[2][1][o0_]);
  asm volatile("s_waitcnt vmcnt(2)" ::: "memory");
  __builtin_amdgcn_s_barrier();

  // --- main loop: 64 uniform tiles (4-unrolled; clamped tail re-stages) ---
#define KCL(x) ((size_t)((x) < KTILES ? (x) : KTILES - 1) * 64)
  for (int tb = 0; tb < KTILES / 4; ++tb) {
    const int t0 = tb * 4;
    TILE4(0, KCL(t0 + 3))
    TILE4(1, KCL(t0 + 4))
    TILE4(2, KCL(t0 + 5))
    TILE4(3, KCL(t0 + 6))
  }
#undef KCL
  asm volatile("s_waitcnt vmcnt(0)" ::: "memory");  // drain before exit

  // --- epilogue: frag j, lane c -> n = nb4 + j (packed full-line stores) ---
  const float s = sp[0];
  const float zpf = (float)zpp[0];
  const int m0 = bm * 256 + wr * 64 + (lane >> 4) * 4;
  const int nb4 = bn * 256 + wc * 64 + ((lane & 15) << 2);
  const int4 cr4 = *(const int4*)(corr + nb4);
  const float4 sw4 = *(const float4*)(swp + nb4);
  const float4 bb4 = *(const float4*)(bias + nb4);
  const float fs0 = s * sw4.x, fs1 = s * sw4.y, fs2 = s * sw4.z, fs3 = s * sw4.w;
#pragma unroll
  for (int i = 0; i < 4; ++i) {
#pragma unroll
    for (int q = 0; q < 4; ++q) {
      const int m = m0 + i * 16 + q;
      const float v0 = fs0 * (float)(acc[i][0][q] + cr4.x) + bb4.x;
      const float v1 = fs1 * (float)(acc[i][1][q] + cr4.y) + bb4.y;
      const float v2 = fs2 * (float)(acc[i][2][q] + cr4.z) + bb4.z;
      const float v3 = fs3 * (float)(acc[i][3][q] + cr4.w) + bb4.w;
      if (WRITE_Q) {
        const int b0i = (int)fminf(fmaxf(rintf(v0 / s) + zpf, 0.f), 255.f) - 128;
        const int b1i = (int)fminf(fmaxf(rintf(v1 / s) + zpf, 0.f), 255.f) - 128;
        const int b2i = (int)fminf(fmaxf(rintf(v2 / s) + zpf, 0.f), 255.f) - 128;
        const int b3i = (int)fminf(fmaxf(rintf(v3 / s) + zpf, 0.f), 255.f) - 128;
        const uint32_t pk = (uint32_t)(b0i & 255) | ((uint32_t)(b1i & 255) << 8) |
                            ((uint32_t)(b2i & 255) << 16) | ((uint32_t)b3i << 24);
        *(uint32_t*)(outq + (size_t)m * N_DIM + nb4) = pk;
      } else {
        float4 o4;
        o4.x = v0; o4.y = v1; o4.z = v2; o4.w = v3;
        *(float4*)(outf + (size_t)m * N_DIM + nb4) = o4;
      }
    }
  }
}

// ---------------------------------------------------------------------------
extern "C" void kernel_launch(void* const* d_in, const int* in_sizes, int n_in,
                              void* d_out, int out_size, void* d_ws, size_t ws_size,
                              hipStream_t stream) {
  const float* x = (const float*)d_in[0];
  const int* wq = (const int*)d_in[1];
  const float* bias = (const float*)d_in[2];
  const float* s_in = (const float*)d_in[3];
  const int* zp_in = (const int*)d_in[4];
  const float* s_w = (const float*)d_in[5];
  float* out = (float*)d_out;

  const size_t WP_BYTES = (size_t)N_DIM * K_DIM;  // 16 MB packed int8 W
  const size_t Q_BYTES = (size_t)M_DIM * K_DIM;   // 32 MB int8 activations
  char* ws = (char*)d_ws;
  char* wp = ws;
  char* q1 = ws + WP_BYTES;
  char* q2 = q1 + Q_BYTES;
  int* corr = (int*)(q2 + Q_BYTES);
  const size_t NEEDED = WP_BYTES + 2 * Q_BYTES + (size_t)N_DIM * sizeof(int);
  if (ws_size < NEEDED) return;

  pack_w_kernel<<<N_DIM, 256, 0, stream>>>(wq, wp, corr, zp_in);
  quant_in_kernel<<<(M_DIM * K_DIM / 4) / 256, 256, 0, stream>>>(x, q1, s_in, zp_in);

  dim3 grid((M_DIM / 256) * (N_DIM / 256));  // 512 blocks
  dim3 blk(1024);
  gemm_kernel<1><<<grid, blk, 0, stream>>>(q1, wp, corr, s_w, bias, s_in, zp_in, q2, nullptr);
  gemm_kernel<1><<<grid, blk, 0, stream>>>(q2, wp, corr, s_w, bias, s_in, zp_in, q1, nullptr);
  gemm_kernel<0><<<grid, blk, 0, stream>>>(q1, wp, corr, s_w, bias, s_in, zp_in, nullptr, out);
}